// Round 9
// baseline (37.871 us; speedup 1.0000x reference)
//
#include <hip/hip_runtime.h>

// MTRNN single step. Live computation after DCE (reference returns only y):
//   io_new = tanh([x|io|cf] @ (0.5*[Wi2io | Wio2io+I | Wcf2io])^T + bsum)
//   y      = tanh(io_new @ Wio2o^T + bio2o)
// cf_new / cs_new dead. bf16 MFMA, f32 accumulate.
// gemm1: A reg-staged f32->bf16 (2 tiles ahead, 2 named reg sets) + ds_write;
// B via global_load_lds from pre-swizzled global. 3 LDS buffers, counted
// vmcnt (never 0 in the loop). gemm2: full gl_lds 3-buffer counted pipeline.

typedef float f32x4 __attribute__((ext_vector_type(4)));
typedef __bf16 bf16x4 __attribute__((ext_vector_type(4)));
typedef __bf16 bf16x8 __attribute__((ext_vector_type(8)));
typedef unsigned short u16x4 __attribute__((ext_vector_type(4)));

__device__ __forceinline__ unsigned short f2bf(float f) {
    unsigned u = __builtin_bit_cast(unsigned, f);
    u += 0x7FFFu + ((u >> 16) & 1u);
    return (unsigned short)(u >> 16);
}

__device__ __forceinline__ float tanh_fast(float x) {
    float e = __expf(2.0f * x);
    return 1.0f - 2.0f * __builtin_amdgcn_rcpf(e + 1.0f);
}

// async global->LDS, 16B per lane. LDS dest is wave-uniform base + lane*16.
__device__ __forceinline__ void gload16(const void* g, void* l) {
    __builtin_amdgcn_global_load_lds(
        (const __attribute__((address_space(1))) void*)g,
        (__attribute__((address_space(3))) void*)l, 16, 0, 0);
}

// counted wait + barrier; lgkmcnt(0) publishes this wave's ds_writes.
#define WAITB(N) asm volatile("s_waitcnt vmcnt(" #N ") lgkmcnt(0)\n\ts_barrier" ::: "memory")

// ---------------------------------------------------------------------------
// Kernel 0: pack weights to bf16, CHUNK-SWIZZLED within each 64-col K-tile:
// element (n,k) -> n*L + (k&~63) + ((((k>>3)&7) ^ (n&7))<<3) + (k&7).
//   wcat[512][1152] = 0.5*[Wi2io | Wio2io + I | Wcf2io]
//   w2s [128][512]  = Wio2o
//   bsum[512]       = 0.5*(bi2io + bio2io + bcf2io)
// ---------------------------------------------------------------------------
__global__ __launch_bounds__(256) void k_convert(
    const float* __restrict__ Wi2io, const float* __restrict__ Wio2io,
    const float* __restrict__ Wcf2io, const float* __restrict__ Wio2o,
    const float* __restrict__ b1, const float* __restrict__ b2,
    const float* __restrict__ b3,
    unsigned short* __restrict__ wcat, unsigned short* __restrict__ w2s,
    float* __restrict__ bsum)
{
    int idx = blockIdx.x * 256 + threadIdx.x;
    if (idx < 147456) {              // 512*1152/4 quads
        int n = idx / 288;
        int k = (idx - n * 288) * 4;
        const float* s;
        if (k < 128)      s = Wi2io  + n * 128 + k;
        else if (k < 640) s = Wio2io + n * 512 + (k - 128);
        else              s = Wcf2io + n * 512 + (k - 640);
        f32x4 v = *(const f32x4*)s;
        u16x4 h;
        #pragma unroll
        for (int t = 0; t < 4; ++t) {
            float f = 0.5f * v[t];
            int kk = k + t;
            if (kk >= 128 && kk < 640 && (kk - 128) == n) f += 0.5f;  // +0.5*I
            h[t] = f2bf(f);
        }
        int ad = n * 1152 + (k & ~63) + ((((k >> 3) & 7) ^ (n & 7)) << 3) + (k & 7);
        *(u16x4*)(wcat + ad) = h;
    } else if (idx < 163840) {       // 128*512/4 quads
        int q = idx - 147456;
        int n = q >> 7;
        int k = (q & 127) * 4;
        f32x4 v = *(const f32x4*)(Wio2o + n * 512 + k);
        u16x4 h; h[0]=f2bf(v[0]); h[1]=f2bf(v[1]); h[2]=f2bf(v[2]); h[3]=f2bf(v[3]);
        int ad = n * 512 + (k & ~63) + ((((k >> 3) & 7) ^ (n & 7)) << 3) + (k & 7);
        *(u16x4*)(w2s + ad) = h;
    } else if (idx < 164352) {
        int n = idx - 163840;
        bsum[n] = 0.5f * (b1[n] + b2[n] + b3[n]);
    }
}

// ---------------------------------------------------------------------------
// Kernel 1: ionew = tanh(Acat @ wcat^T + bsum), bf16 out (stored swizzled).
// M=8192 N=512 K=1152. BM=128 BN=128 BK=64, 512 thr (8 waves 4m x 2n, wave
// 32x64). Grid 256 = 1 block/CU, XCD-affine (8 panels x 4 colb per XCD).
// LDS 3 x (A bf16 16KB | B bf16 16KB) = 96KB.
// A: reg-staged 2-ahead (glob f32 -> cvt -> ds_write bf16, XOR-swizzled).
// B: gl_lds 2-ahead from pre-swizzled global. Steady-state WAITB(2).
// ---------------------------------------------------------------------------
__global__ __launch_bounds__(512, 2) void k_gemm1(
    const float* __restrict__ x, const float* __restrict__ io,
    const float* __restrict__ cf,
    const unsigned short* __restrict__ wcat,
    const float* __restrict__ bsum,
    unsigned short* __restrict__ ionew)
{
    __shared__ __align__(16) char lds[3][32768];   // A @0 (16KB), B @16384

    const int tid = threadIdx.x, b = blockIdx.x;
    const int xcd = b & 7, idx = b >> 3;           // idx 0..31
    const int m0 = ((xcd << 3) | (idx & 7)) << 7;  // panel*128
    const int n0 = (idx >> 3) << 7;                // colb*128

    const int lane = tid & 63, wid = tid >> 6;
    const int li = lane & 15, lh = lane >> 4;
    const int wm = (wid >> 1) << 5;       // 0/32/64/96
    const int wn = (wid & 1) << 6;        // 0/64

    // A staging map: thread owns rows {row0, row0+64}, chunk ch (8 f32 each)
    const int row0 = tid >> 3, ch = tid & 7;
    const size_t aoffx0 = (size_t)(m0 + row0) * 128 + ch * 8;
    const size_t aoffx1 = (size_t)(m0 + row0 + 64) * 128 + ch * 8;
    const size_t aoffs0 = (size_t)(m0 + row0) * 512 + ch * 8;
    const size_t aoffs1 = (size_t)(m0 + row0 + 64) * 512 + ch * 8;
    const int lwa0 = row0 * 128 + ((ch ^ (row0 & 7)) << 4);   // +8192 for +64 rows
    // B staging: gl_lds, rows linear (global pre-swizzled)
    int b_off[2];
    #pragma unroll
    for (int j = 0; j < 2; ++j) {
        int rb = ((wid << 1) + j) * 8 + (lane >> 3);
        b_off[j] = (n0 + rb) * 1152 + ((lane & 7) << 3);
    }
    const int adstB = wid << 11;   // + j<<10

    f32x4 qa0, qa1, qa2, qa3, ra0, ra1, ra2, ra3;   // 2 named A reg sets
    f32x4 zz = {0.f, 0.f, 0.f, 0.f};
    f32x4 acc[2][4];
    #pragma unroll
    for (int i = 0; i < 2; ++i)
        #pragma unroll
        for (int j = 0; j < 4; ++j) acc[i][j] = zz;

#define ALOAD(S0, S1, S2, S3, KT) do {                                         \
        int K_ = (KT);                                                         \
        const float* sp; size_t o0, o1;                                        \
        if (K_ < 2)       { sp = x  + (K_ << 6);        o0 = aoffx0; o1 = aoffx1; } \
        else if (K_ < 10) { sp = io + ((K_ - 2) << 6);  o0 = aoffs0; o1 = aoffs1; } \
        else              { sp = cf + ((K_ - 10) << 6); o0 = aoffs0; o1 = aoffs1; } \
        S0 = *(const f32x4*)(sp + o0);                                         \
        S1 = *(const f32x4*)(sp + o0 + 4);                                     \
        S2 = *(const f32x4*)(sp + o1);                                         \
        S3 = *(const f32x4*)(sp + o1 + 4);                                     \
    } while (0)

#define BSTAGE(KT, BUF) do {                                                   \
        const unsigned short* wp = wcat + ((KT) << 6);                         \
        char* B_ = (BUF) + 16384;                                              \
        gload16(wp + b_off[0], B_ + adstB);                                    \
        gload16(wp + b_off[1], B_ + adstB + 1024);                             \
    } while (0)

#define AWRITE(S0, S1, S2, S3, BUF) do {                                       \
        char* A_ = (BUF);                                                      \
        bf16x4 h0 = __builtin_convertvector(S0, bf16x4);                       \
        bf16x4 h1 = __builtin_convertvector(S1, bf16x4);                       \
        bf16x4 h2 = __builtin_convertvector(S2, bf16x4);                       \
        bf16x4 h3 = __builtin_convertvector(S3, bf16x4);                       \
        *(bf16x8*)(A_ + lwa0) =                                                \
            __builtin_shufflevector(h0, h1, 0,1,2,3,4,5,6,7);                  \
        *(bf16x8*)(A_ + lwa0 + 8192) =                                         \
            __builtin_shufflevector(h2, h3, 0,1,2,3,4,5,6,7);                  \
    } while (0)

#define COMPUTE1(BUF) do {                                                     \
        const char* A_ = (BUF); const char* B_ = (BUF) + 16384;                \
        _Pragma("unroll")                                                      \
        for (int ks = 0; ks < 2; ++ks) {                                       \
            int c = ks * 4 + lh;                                               \
            bf16x8 af[2];                                                      \
            _Pragma("unroll")                                                  \
            for (int mi = 0; mi < 2; ++mi) {                                   \
                int r = wm + mi * 16 + li;                                     \
                af[mi] = *(const bf16x8*)(A_ + r * 128 + ((c ^ (r & 7)) << 4));\
            }                                                                  \
            _Pragma("unroll")                                                  \
            for (int nj = 0; nj < 4; ++nj) {                                   \
                int rb = wn + nj * 16 + li;                                    \
                bf16x8 bv = *(const bf16x8*)(B_ + rb * 128 +                   \
                                             ((c ^ (rb & 7)) << 4));           \
                acc[0][nj] = __builtin_amdgcn_mfma_f32_16x16x32_bf16(          \
                    af[0], bv, acc[0][nj], 0, 0, 0);                           \
                acc[1][nj] = __builtin_amdgcn_mfma_f32_16x16x32_bf16(          \
                    af[1], bv, acc[1][nj], 0, 0, 0);                           \
            }                                                                  \
        }                                                                      \
    } while (0)

    char* p0 = lds[0]; char* p1 = lds[1]; char* p2 = lds[2];
#define ROT() do { char* t_ = p0; p0 = p1; p1 = p2; p2 = t_; } while (0)

    // prologue: A0->Q, B0->p0, A1->R, B1->p1; retire A0; write A0.
    ALOAD(qa0, qa1, qa2, qa3, 0);
    BSTAGE(0, p0);
    ALOAD(ra0, ra1, ra2, ra3, 1);
    BSTAGE(1, p1);
    asm volatile("s_waitcnt vmcnt(8)" ::: "memory");   // A0 retired
    AWRITE(qa0, qa1, qa2, qa3, p0);

    // steady state: WAITB(2) retires {B(t), A(t+1)}; B(t+1) + stage(t+2) fly.
    #pragma unroll 1
    for (int i = 0; i < 8; ++i) {
        // t = 2i (even): stage t+2 into Q
        WAITB(2);
        ALOAD(qa0, qa1, qa2, qa3, 2 * i + 2);
        BSTAGE(2 * i + 2, p2);
        AWRITE(ra0, ra1, ra2, ra3, p1);
        COMPUTE1(p0);
        ROT();
        // t = 2i+1 (odd): stage t+2 into R
        WAITB(2);
        if (2 * i + 3 < 18) {
            ALOAD(ra0, ra1, ra2, ra3, 2 * i + 3);
            BSTAGE(2 * i + 3, p2);
        }
        AWRITE(qa0, qa1, qa2, qa3, p1);
        COMPUTE1(p0);
        ROT();
    }
    // t = 16: no stage(18); A(17) is in R
    WAITB(2);
    AWRITE(ra0, ra1, ra2, ra3, p1);
    COMPUTE1(p0);
    ROT();
    // t = 17
    WAITB(0);
    COMPUTE1(p0);
#undef ALOAD
#undef BSTAGE
#undef AWRITE
#undef COMPUTE1
#undef ROT

    // epilogue: bias+tanh, store bf16 chunk-swizzled (gemm2-ready layout)
    #pragma unroll
    for (int nj = 0; nj < 4; ++nj) {
        int gn = n0 + wn + nj * 16 + li;
        float bb = bsum[gn];
        #pragma unroll
        for (int mi = 0; mi < 2; ++mi) {
            #pragma unroll
            for (int r = 0; r < 4; ++r) {
                int gm = m0 + wm + mi * 16 + (lh << 2) + r;
                float v = tanh_fast(acc[mi][nj][r] + bb);
                int ad = gm * 512 + (gn & ~63) +
                         ((((gn >> 3) & 7) ^ (gm & 7)) << 3) + (gn & 7);
                ionew[ad] = f2bf(v);
            }
        }
    }
}

// ---------------------------------------------------------------------------
// Kernel 2: y = tanh(ionew @ w2s^T + bio2o). M=8192 N=128 K=512.
// BM=32 BN=128(full) BK=64, 256 thr (4 waves, wave 32x32). Grid 256.
// 3-buffer counted pipeline (5 gl_lds/stage -> WAITB(5)).
// ---------------------------------------------------------------------------
__global__ __launch_bounds__(256, 2) void k_gemm2(
    const unsigned short* __restrict__ ionew,
    const unsigned short* __restrict__ w2s,
    const float* __restrict__ b4,
    float* __restrict__ out)
{
    __shared__ __align__(16) char lds[3][20480];   // A @0 (4KB), B @4096 (16KB)

    const int tid = threadIdx.x, b = blockIdx.x;
    const int xcd = b & 7, idx = b >> 3;           // idx 0..31
    const int m0 = ((xcd << 5) | idx) << 5;        // matches gemm1 writer XCD

    const int lane = tid & 63, wid = tid >> 6;
    const int li = lane & 15, lh = lane >> 4;
    const int wn = wid << 5;                       // 32 out-cols per wave

    const int a2_off = (m0 + (wid << 3) + (lane >> 3)) * 512 + ((lane & 7) << 3);
    int b2_off[4];
    #pragma unroll
    for (int j = 0; j < 4; ++j)
        b2_off[j] = ((wid << 5) + 8 * j + (lane >> 3)) * 512 + ((lane & 7) << 3);

    f32x4 zz = {0.f, 0.f, 0.f, 0.f};
    f32x4 acc[2][2];
    acc[0][0] = zz; acc[0][1] = zz; acc[1][0] = zz; acc[1][1] = zz;

#define STAGE2(KT, BUF) do {                                                   \
        int K_ = (KT);                                                         \
        char* A_ = (BUF); char* B_ = (BUF) + 4096;                             \
        gload16(ionew + a2_off + (K_ << 6), A_ + (wid << 10));                 \
        _Pragma("unroll")                                                      \
        for (int j = 0; j < 4; ++j)                                            \
            gload16(w2s + b2_off[j] + (K_ << 6), B_ + (wid << 12) + j * 1024); \
    } while (0)

#define COMPUTE2(BUF) do {                                                     \
        const char* A_ = (BUF); const char* B_ = (BUF) + 4096;                 \
        _Pragma("unroll")                                                      \
        for (int ks = 0; ks < 2; ++ks) {                                       \
            int c = ks * 4 + lh;                                               \
            bf16x8 av[2];                                                      \
            _Pragma("unroll")                                                  \
            for (int mi = 0; mi < 2; ++mi) {                                   \
                int r = mi * 16 + li;                                          \
                av[mi] = *(const bf16x8*)(A_ + r * 128 + ((c ^ (r & 7)) << 4));\
            }                                                                  \
            _Pragma("unroll")                                                  \
            for (int nj = 0; nj < 2; ++nj) {                                   \
                int rb = wn + nj * 16 + li;                                    \
                bf16x8 bv = *(const bf16x8*)(B_ + rb * 128 +                   \
                                             ((c ^ (rb & 7)) << 4));           \
                acc[0][nj] = __builtin_amdgcn_mfma_f32_16x16x32_bf16(          \
                    av[0], bv, acc[0][nj], 0, 0, 0);                           \
                acc[1][nj] = __builtin_amdgcn_mfma_f32_16x16x32_bf16(          \
                    av[1], bv, acc[1][nj], 0, 0, 0);                           \
            }                                                                  \
        }                                                                      \
    } while (0)

    STAGE2(0, lds[0]);
    STAGE2(1, lds[1]);
    char* p0 = lds[0]; char* p1 = lds[1]; char* p2 = lds[2];
    #pragma unroll 1
    for (int t = 0; t < 7; ++t) {
        WAITB(5);
        if (t + 2 < 8) STAGE2(t + 2, p2);
        COMPUTE2(p0);
        char* tmp = p0; p0 = p1; p1 = p2; p2 = tmp;
    }
    WAITB(0);
    COMPUTE2(p0);                          // tile 7
#undef STAGE2
#undef COMPUTE2

    #pragma unroll
    for (int nj = 0; nj < 2; ++nj) {
        int n = wn + nj * 16 + li;
        float bb = b4[n];
        #pragma unroll
        for (int mi = 0; mi < 2; ++mi) {
            #pragma unroll
            for (int r = 0; r < 4; ++r) {
                int gm = m0 + mi * 16 + (lh << 2) + r;
                out[(size_t)gm * 128 + n] = tanh_fast(acc[mi][nj][r] + bb);
            }
        }
    }
}

// ---------------------------------------------------------------------------
extern "C" void kernel_launch(void* const* d_in, const int* in_sizes, int n_in,
                              void* d_out, int out_size, void* d_ws, size_t ws_size,
                              hipStream_t stream)
{
    const float* x      = (const float*)d_in[0];
    const float* io     = (const float*)d_in[1];
    const float* cf     = (const float*)d_in[2];
    // d_in[3] cs_state: dead (does not feed y)
    const float* Wi2io  = (const float*)d_in[4];
    const float* bi2io  = (const float*)d_in[5];
    const float* Wio2o  = (const float*)d_in[6];
    const float* bio2o  = (const float*)d_in[7];
    const float* Wio2io = (const float*)d_in[8];
    const float* bio2io = (const float*)d_in[9];
    const float* Wcf2io = (const float*)d_in[12];
    const float* bcf2io = (const float*)d_in[13];
    float* out = (float*)d_out;

    // ws: wcat 1,179,648 | w2s 131,072 | bsum 2,048 | ionew 8,388,608
    char* ws = (char*)d_ws;
    unsigned short* wcat  = (unsigned short*)ws;
    unsigned short* w2s   = (unsigned short*)(ws + 1179648);
    float*          bsum  = (float*)(ws + 1310720);
    unsigned short* ionew = (unsigned short*)(ws + 1312768);

    hipLaunchKernelGGL(k_convert, dim3(642), dim3(256), 0, stream,
                       Wi2io, Wio2io, Wcf2io, Wio2o, bi2io, bio2io, bcf2io,
                       wcat, w2s, bsum);
    hipLaunchKernelGGL(k_gemm1, dim3(256), dim3(512), 0, stream,
                       x, io, cf, wcat, bsum, ionew);
    hipLaunchKernelGGL(k_gemm2, dim3(256), dim3(256), 0, stream,
                       ionew, w2s, bio2o, out);
}

// Round 10
// 35.188 us; speedup vs baseline: 1.0762x; 1.0762x over previous
//
#include <hip/hip_runtime.h>

// MTRNN single step. Live computation after DCE (reference returns only y):
//   io_new = tanh([x|io|cf] @ (0.5*[Wi2io | Wio2io+I | Wcf2io])^T + bsum)
//   y      = tanh(io_new @ Wio2o^T + bio2o)
// cf_new / cs_new dead. bf16 MFMA, f32 accumulate.
// gemm1: A staged f32 via global_load_lds (3-buf, 2-ahead, counted vmcnt);
// B read DIRECTLY from global in MFMA-fragment-contiguous layout (1 coalesced
// 16B/lane load per frag, L1-resident) -> B never touches LDS.
// gemm2: r8's proven full-gl_lds 3-buffer counted pipeline (unchanged).

typedef float f32x4 __attribute__((ext_vector_type(4)));
typedef __bf16 bf16x4 __attribute__((ext_vector_type(4)));
typedef __bf16 bf16x8 __attribute__((ext_vector_type(8)));
typedef unsigned short u16x4 __attribute__((ext_vector_type(4)));

__device__ __forceinline__ unsigned short f2bf(float f) {
    unsigned u = __builtin_bit_cast(unsigned, f);
    u += 0x7FFFu + ((u >> 16) & 1u);
    return (unsigned short)(u >> 16);
}

__device__ __forceinline__ float tanh_fast(float x) {
    float e = __expf(2.0f * x);
    return 1.0f - 2.0f * __builtin_amdgcn_rcpf(e + 1.0f);
}

// async global->LDS, 16B per lane. LDS dest is wave-uniform base + lane*16.
__device__ __forceinline__ void gload16(const void* g, void* l) {
    __builtin_amdgcn_global_load_lds(
        (const __attribute__((address_space(1))) void*)g,
        (__attribute__((address_space(3))) void*)l, 16, 0, 0);
}

// counted wait + barrier: keep N VMEM ops in flight across the barrier.
#define WAITB(N) asm volatile("s_waitcnt vmcnt(" #N ")\n\ts_barrier" ::: "memory")

// ---------------------------------------------------------------------------
// Kernel 0: pack weights to bf16.
//   wfrag: wcat = 0.5*[Wi2io | Wio2io + I | Wcf2io] in FRAG-CONTIGUOUS order:
//     element (n,k) -> frag (kt=k>>6, c16=n>>4, ks=(k>>5)&1), lane
//     l=(n&15)|(((k>>3)&3)<<4), elem e=k&7;
//     addr = ((((kt<<5)|c16)<<1)|ks)*512 + l*8 + e.
//   w2s [128][512]: Wio2o, chunk-XOR-swizzled per 64-col K-tile (for gl_lds).
//   bsum[512] = 0.5*(bi2io + bio2io + bcf2io)
// ---------------------------------------------------------------------------
__global__ __launch_bounds__(256) void k_convert(
    const float* __restrict__ Wi2io, const float* __restrict__ Wio2io,
    const float* __restrict__ Wcf2io, const float* __restrict__ Wio2o,
    const float* __restrict__ b1, const float* __restrict__ b2,
    const float* __restrict__ b3,
    unsigned short* __restrict__ wfrag, unsigned short* __restrict__ w2s,
    float* __restrict__ bsum)
{
    int idx = blockIdx.x * 256 + threadIdx.x;
    if (idx < 147456) {              // 512*1152/4 quads
        int n = idx / 288;
        int k = (idx - n * 288) * 4;
        const float* s;
        if (k < 128)      s = Wi2io  + n * 128 + k;
        else if (k < 640) s = Wio2io + n * 512 + (k - 128);
        else              s = Wcf2io + n * 512 + (k - 640);
        f32x4 v = *(const f32x4*)s;
        u16x4 h;
        #pragma unroll
        for (int t = 0; t < 4; ++t) {
            float f = 0.5f * v[t];
            int kk = k + t;
            if (kk >= 128 && kk < 640 && (kk - 128) == n) f += 0.5f;  // +0.5*I
            h[t] = f2bf(f);
        }
        int kt = k >> 6, ks = (k >> 5) & 1, c16 = n >> 4;
        int l = (n & 15) | (((k >> 3) & 3) << 4);
        int ad = ((((kt << 5) | c16) << 1) | ks) * 512 + l * 8 + (k & 7);
        *(u16x4*)(wfrag + ad) = h;
    } else if (idx < 163840) {       // 128*512/4 quads
        int q = idx - 147456;
        int n = q >> 7;
        int k = (q & 127) * 4;
        f32x4 v = *(const f32x4*)(Wio2o + n * 512 + k);
        u16x4 h; h[0]=f2bf(v[0]); h[1]=f2bf(v[1]); h[2]=f2bf(v[2]); h[3]=f2bf(v[3]);
        int ad = n * 512 + (k & ~63) + ((((k >> 3) & 7) ^ (n & 7)) << 3) + (k & 7);
        *(u16x4*)(w2s + ad) = h;
    } else if (idx < 164352) {
        int n = idx - 163840;
        bsum[n] = 0.5f * (b1[n] + b2[n] + b3[n]);
    }
}

// ---------------------------------------------------------------------------
// Kernel 1: ionew = tanh(Acat @ wcat^T + bsum), bf16 out (stored swizzled).
// M=8192 N=512 K=1152. BM=64 BN=128 BK=64, 512 thr (8 waves 2m x 4n, wave
// 32x32). Grid 512 = 2 blocks/CU. LDS = 3 x (A 64x64 f32 = 16KB) = 48KB.
// A: gl_lds 2 tiles ahead (chunk-XOR in source offsets), WAITB(2) steady.
// B: direct per-frag global loads from wfrag (L1-resident, no LDS).
// XCD-affine: 16 panels x 4 col-blocks per XCD.
// ---------------------------------------------------------------------------
__global__ __launch_bounds__(512, 4) void k_gemm1(
    const float* __restrict__ x, const float* __restrict__ io,
    const float* __restrict__ cf,
    const unsigned short* __restrict__ wfrag,
    const float* __restrict__ bsum,
    unsigned short* __restrict__ ionew)
{
    __shared__ __align__(16) char lds[3][16384];

    const int tid = threadIdx.x, b = blockIdx.x;
    const int xcd = b & 7, idx = b >> 3;            // idx 0..63
    const int m0 = ((xcd << 4) | (idx & 15)) << 6;  // panel*64
    const int n0 = (idx >> 4) << 7;                 // colb*128

    const int lane = tid & 63, wid = tid >> 6;
    const int li = lane & 15, lh = lane >> 4;
    const int wm = (wid >> 2) << 5;       // 0/32
    const int wn = (wid & 3) << 5;        // 0/32/64/96

    // A staging: wave w issues 2 gl_lds; lane covers row rw, 16B chunk cs.
    int a_off_x[2], a_off_s[2];
    #pragma unroll
    for (int j = 0; j < 2; ++j) {
        int rw = (wid << 3) + (j << 2) + (lane >> 4);    // row 0..63
        int cs = (lane & 15) ^ (rw & 15);                // swizzled 16B chunk
        a_off_x[j] = (m0 + rw) * 128 + cs * 4;
        a_off_s[j] = (m0 + rw) * 512 + cs * 4;
    }
    const int adst = wid << 11;          // + j<<10

    // B frag base: wave's first c16 group; frag addr = base + kt*32768
    //              + nj*1024 + ks*512 (elements).
    const unsigned short* fb = wfrag + (size_t)(((n0 + wn) >> 4)) * 1024 + lane * 8;

    f32x4 zz = {0.f, 0.f, 0.f, 0.f};
    f32x4 acc[2][2];
    acc[0][0] = zz; acc[0][1] = zz; acc[1][0] = zz; acc[1][1] = zz;
    bf16x8 b00, b01, b10, b11;           // [nj][ks]

#define ASTAGE(KT, BUF) do {                                                   \
        int K_ = (KT);                                                         \
        char* A_ = (BUF);                                                      \
        if (K_ < 2) {                                                          \
            const float* sp = x + (K_ << 6);                                   \
            gload16(sp + a_off_x[0], A_ + adst);                               \
            gload16(sp + a_off_x[1], A_ + adst + 1024);                        \
        } else if (K_ < 10) {                                                  \
            const float* sp = io + ((K_ - 2) << 6);                            \
            gload16(sp + a_off_s[0], A_ + adst);                               \
            gload16(sp + a_off_s[1], A_ + adst + 1024);                        \
        } else {                                                               \
            const float* sp = cf + ((K_ - 10) << 6);                           \
            gload16(sp + a_off_s[0], A_ + adst);                               \
            gload16(sp + a_off_s[1], A_ + adst + 1024);                        \
        }                                                                      \
    } while (0)

#define BLOAD(KT) do {                                                         \
        const unsigned short* fp = fb + (size_t)(KT) * 32768;                  \
        b00 = *(const bf16x8*)(fp);                                            \
        b01 = *(const bf16x8*)(fp + 512);                                      \
        b10 = *(const bf16x8*)(fp + 1024);                                     \
        b11 = *(const bf16x8*)(fp + 1536);                                     \
    } while (0)

#define COMPUTE1(BUF) do {                                                     \
        const char* A_ = (BUF);                                                \
        _Pragma("unroll")                                                      \
        for (int ks = 0; ks < 2; ++ks) {                                       \
            bf16x8 af[2];                                                      \
            _Pragma("unroll")                                                  \
            for (int mi = 0; mi < 2; ++mi) {                                   \
                int r = wm + mi * 16 + li;                                     \
                int c0 = ks * 8 + lh * 2;                                      \
                f32x4 a0 = *(const f32x4*)(A_ + r * 256 +                      \
                                           ((c0 ^ (r & 15)) << 4));            \
                f32x4 a1 = *(const f32x4*)(A_ + r * 256 +                      \
                                           (((c0 + 1) ^ (r & 15)) << 4));      \
                bf16x4 h0 = __builtin_convertvector(a0, bf16x4);               \
                bf16x4 h1 = __builtin_convertvector(a1, bf16x4);               \
                af[mi] = __builtin_shufflevector(h0, h1, 0,1,2,3,4,5,6,7);     \
            }                                                                  \
            bf16x8 bv0 = ks ? b01 : b00;                                       \
            bf16x8 bv1 = ks ? b11 : b10;                                       \
            acc[0][0] = __builtin_amdgcn_mfma_f32_16x16x32_bf16(               \
                af[0], bv0, acc[0][0], 0, 0, 0);                               \
            acc[1][0] = __builtin_amdgcn_mfma_f32_16x16x32_bf16(               \
                af[1], bv0, acc[1][0], 0, 0, 0);                               \
            acc[0][1] = __builtin_amdgcn_mfma_f32_16x16x32_bf16(               \
                af[0], bv1, acc[0][1], 0, 0, 0);                               \
            acc[1][1] = __builtin_amdgcn_mfma_f32_16x16x32_bf16(               \
                af[1], bv1, acc[1][1], 0, 0, 0);                               \
        }                                                                      \
    } while (0)

    ASTAGE(0, lds[0]);
    ASTAGE(1, lds[1]);
    char* p0 = lds[0]; char* p1 = lds[1]; char* p2 = lds[2];
    #pragma unroll 1
    for (int t = 0; t < 18; ++t) {
        if (t < 17) { WAITB(2); } else { WAITB(0); }
        BLOAD(t);                            // L1/L2-resident frag loads
        if (t + 2 < 18) ASTAGE(t + 2, p2);   // A 2 tiles ahead
        COMPUTE1(p0);
        char* tmp = p0; p0 = p1; p1 = p2; p2 = tmp;
    }
#undef ASTAGE
#undef BLOAD
#undef COMPUTE1

    // epilogue: bias+tanh, store bf16 chunk-swizzled (gemm2-ready layout)
    #pragma unroll
    for (int nj = 0; nj < 2; ++nj) {
        int gn = n0 + wn + nj * 16 + li;
        float bb = bsum[gn];
        #pragma unroll
        for (int mi = 0; mi < 2; ++mi) {
            #pragma unroll
            for (int r = 0; r < 4; ++r) {
                int gm = m0 + wm + mi * 16 + (lh << 2) + r;
                float v = tanh_fast(acc[mi][nj][r] + bb);
                int ad = gm * 512 + (gn & ~63) +
                         ((((gn >> 3) & 7) ^ (gm & 7)) << 3) + (gn & 7);
                ionew[ad] = f2bf(v);
            }
        }
    }
}

// ---------------------------------------------------------------------------
// Kernel 2: y = tanh(ionew @ w2s^T + bio2o). M=8192 N=128 K=512.
// BM=32 BN=128(full) BK=64, 256 thr (4 waves, wave 32x32). Grid 256.
// 3-buffer counted pipeline (5 gl_lds/stage -> WAITB(5)). [r8, unchanged]
// ---------------------------------------------------------------------------
__global__ __launch_bounds__(256, 2) void k_gemm2(
    const unsigned short* __restrict__ ionew,
    const unsigned short* __restrict__ w2s,
    const float* __restrict__ b4,
    float* __restrict__ out)
{
    __shared__ __align__(16) char lds[3][20480];   // A @0 (4KB), B @4096 (16KB)

    const int tid = threadIdx.x, b = blockIdx.x;
    const int xcd = b & 7, idx = b >> 3;           // idx 0..31
    const int m0 = ((xcd << 5) | idx) << 5;        // matches gemm1 writer XCD

    const int lane = tid & 63, wid = tid >> 6;
    const int li = lane & 15, lh = lane >> 4;
    const int wn = wid << 5;                       // 32 out-cols per wave

    const int a2_off = (m0 + (wid << 3) + (lane >> 3)) * 512 + ((lane & 7) << 3);
    int b2_off[4];
    #pragma unroll
    for (int j = 0; j < 4; ++j)
        b2_off[j] = ((wid << 5) + 8 * j + (lane >> 3)) * 512 + ((lane & 7) << 3);

    f32x4 zz = {0.f, 0.f, 0.f, 0.f};
    f32x4 acc[2][2];
    acc[0][0] = zz; acc[0][1] = zz; acc[1][0] = zz; acc[1][1] = zz;

#define STAGE2(KT, BUF) do {                                                   \
        int K_ = (KT);                                                         \
        char* A_ = (BUF); char* B_ = (BUF) + 4096;                             \
        gload16(ionew + a2_off + (K_ << 6), A_ + (wid << 10));                 \
        _Pragma("unroll")                                                      \
        for (int j = 0; j < 4; ++j)                                            \
            gload16(w2s + b2_off[j] + (K_ << 6), B_ + (wid << 12) + j * 1024); \
    } while (0)

#define COMPUTE2(BUF) do {                                                     \
        const char* A_ = (BUF); const char* B_ = (BUF) + 4096;                 \
        _Pragma("unroll")                                                      \
        for (int ks = 0; ks < 2; ++ks) {                                       \
            int c = ks * 4 + lh;                                               \
            bf16x8 av[2];                                                      \
            _Pragma("unroll")                                                  \
            for (int mi = 0; mi < 2; ++mi) {                                   \
                int r = mi * 16 + li;                                          \
                av[mi] = *(const bf16x8*)(A_ + r * 128 + ((c ^ (r & 7)) << 4));\
            }                                                                  \
            _Pragma("unroll")                                                  \
            for (int nj = 0; nj < 2; ++nj) {                                   \
                int rb = wn + nj * 16 + li;                                    \
                bf16x8 bv = *(const bf16x8*)(B_ + rb * 128 +                   \
                                             ((c ^ (rb & 7)) << 4));           \
                acc[0][nj] = __builtin_amdgcn_mfma_f32_16x16x32_bf16(          \
                    av[0], bv, acc[0][nj], 0, 0, 0);                           \
                acc[1][nj] = __builtin_amdgcn_mfma_f32_16x16x32_bf16(          \
                    av[1], bv, acc[1][nj], 0, 0, 0);                           \
            }                                                                  \
        }                                                                      \
    } while (0)

    STAGE2(0, lds[0]);
    STAGE2(1, lds[1]);
    char* p0 = lds[0]; char* p1 = lds[1]; char* p2 = lds[2];
    #pragma unroll 1
    for (int t = 0; t < 7; ++t) {
        WAITB(5);
        if (t + 2 < 8) STAGE2(t + 2, p2);
        COMPUTE2(p0);
        char* tmp = p0; p0 = p1; p1 = p2; p2 = tmp;
    }
    WAITB(0);
    COMPUTE2(p0);                          // tile 7
#undef STAGE2
#undef COMPUTE2

    #pragma unroll
    for (int nj = 0; nj < 2; ++nj) {
        int n = wn + nj * 16 + li;
        float bb = b4[n];
        #pragma unroll
        for (int mi = 0; mi < 2; ++mi) {
            #pragma unroll
            for (int r = 0; r < 4; ++r) {
                int gm = m0 + mi * 16 + (lh << 2) + r;
                out[(size_t)gm * 128 + n] = tanh_fast(acc[mi][nj][r] + bb);
            }
        }
    }
}

// ---------------------------------------------------------------------------
extern "C" void kernel_launch(void* const* d_in, const int* in_sizes, int n_in,
                              void* d_out, int out_size, void* d_ws, size_t ws_size,
                              hipStream_t stream)
{
    const float* x      = (const float*)d_in[0];
    const float* io     = (const float*)d_in[1];
    const float* cf     = (const float*)d_in[2];
    // d_in[3] cs_state: dead (does not feed y)
    const float* Wi2io  = (const float*)d_in[4];
    const float* bi2io  = (const float*)d_in[5];
    const float* Wio2o  = (const float*)d_in[6];
    const float* bio2o  = (const float*)d_in[7];
    const float* Wio2io = (const float*)d_in[8];
    const float* bio2io = (const float*)d_in[9];
    const float* Wcf2io = (const float*)d_in[12];
    const float* bcf2io = (const float*)d_in[13];
    float* out = (float*)d_out;

    // ws: wfrag 1,179,648 | w2s 131,072 | bsum 2,048 | ionew 8,388,608
    char* ws = (char*)d_ws;
    unsigned short* wfrag = (unsigned short*)ws;
    unsigned short* w2s   = (unsigned short*)(ws + 1179648);
    float*          bsum  = (float*)(ws + 1310720);
    unsigned short* ionew = (unsigned short*)(ws + 1312768);

    hipLaunchKernelGGL(k_convert, dim3(642), dim3(256), 0, stream,
                       Wi2io, Wio2io, Wcf2io, Wio2o, bi2io, bio2io, bcf2io,
                       wfrag, w2s, bsum);
    hipLaunchKernelGGL(k_gemm1, dim3(512), dim3(512), 0, stream,
                       x, io, cf, wfrag, bsum, ionew);
    hipLaunchKernelGGL(k_gemm2, dim3(256), dim3(256), 0, stream,
                       ionew, w2s, bio2o, out);
}

// Round 11
// 33.471 us; speedup vs baseline: 1.1314x; 1.0513x over previous
//
#include <hip/hip_runtime.h>

// MTRNN single step. Live computation after DCE (reference returns only y):
//   io_new = tanh([x|io|cf] @ (0.5*[Wi2io | Wio2io+I | Wcf2io])^T + bsum)
//   y      = tanh(io_new @ Wio2o^T + bio2o)
// cf_new / cs_new dead. bf16 MFMA, f32 accumulate.
// r11: A is pre-converted to bf16 ONCE (k_prep, HBM-bound) into a
// chunk-XOR-pre-swizzled layout, so gemm1 stages HALF the bytes and its
// A panels fit per-XCD L2 (295KB*8 = 2.4MB < 4MB) -> refetches are L2 hits.
// gemm1/gemm2: r8's proven 3-buffer counted-vmcnt gl_lds pipeline.

typedef float f32x4 __attribute__((ext_vector_type(4)));
typedef __bf16 bf16x4 __attribute__((ext_vector_type(4)));
typedef __bf16 bf16x8 __attribute__((ext_vector_type(8)));
typedef unsigned short u16x4 __attribute__((ext_vector_type(4)));

__device__ __forceinline__ unsigned short f2bf(float f) {
    unsigned u = __builtin_bit_cast(unsigned, f);
    u += 0x7FFFu + ((u >> 16) & 1u);
    return (unsigned short)(u >> 16);
}

__device__ __forceinline__ float tanh_fast(float x) {
    float e = __expf(2.0f * x);
    return 1.0f - 2.0f * __builtin_amdgcn_rcpf(e + 1.0f);
}

// async global->LDS, 16B per lane. LDS dest is wave-uniform base + lane*16.
__device__ __forceinline__ void gload16(const void* g, void* l) {
    __builtin_amdgcn_global_load_lds(
        (const __attribute__((address_space(1))) void*)g,
        (__attribute__((address_space(3))) void*)l, 16, 0, 0);
}

// counted wait + barrier: keep deeper tiles' loads in flight across it.
#define WAITB(N) asm volatile("s_waitcnt vmcnt(" #N ")\n\ts_barrier" ::: "memory")

// Chunk-XOR swizzled address for element (row, k) in a [*, L] bf16 matrix:
// within each 64-col K-tile, 16B chunk slot = ((k>>3)&7) ^ (row&7).
__device__ __forceinline__ int swz_ad(int row, int k, int L) {
    return row * L + (k & ~63) + ((((k >> 3) & 7) ^ (row & 7)) << 3) + (k & 7);
}

// ---------------------------------------------------------------------------
// Kernel 0 (prep): one memory-bound pass producing all bf16 operands.
//   abf16[8192][1152] = bf16([x | io | cf])            (chunk-XOR swizzled)
//   wcat [512][1152]  = 0.5*[Wi2io | Wio2io+I | Wcf2io] (chunk-XOR swizzled)
//   w2s  [128][512]   = Wio2o                           (chunk-XOR swizzled)
//   bsum [512]        = 0.5*(bi2io + bio2io + bcf2io)
// Task = one 16B output chunk (8 bf16). Grid 4930 x 256.
// ---------------------------------------------------------------------------
__global__ __launch_bounds__(256) void k_prep(
    const float* __restrict__ x, const float* __restrict__ io,
    const float* __restrict__ cf,
    const float* __restrict__ Wi2io, const float* __restrict__ Wio2io,
    const float* __restrict__ Wcf2io, const float* __restrict__ Wio2o,
    const float* __restrict__ b1, const float* __restrict__ b2,
    const float* __restrict__ b3,
    unsigned short* __restrict__ abf16, unsigned short* __restrict__ wcat,
    unsigned short* __restrict__ w2s, float* __restrict__ bsum)
{
    int idx = blockIdx.x * 256 + threadIdx.x;
    if (idx < 1179648) {                 // A: 8192 rows x 144 chunks
        int m = idx / 144;
        int k = (idx - m * 144) * 8;
        const float* s;
        if (k < 128)      s = x  + m * 128 + k;
        else if (k < 640) s = io + m * 512 + (k - 128);
        else              s = cf + m * 512 + (k - 640);
        f32x4 v0 = *(const f32x4*)s;
        f32x4 v1 = *(const f32x4*)(s + 4);
        bf16x4 h0 = __builtin_convertvector(v0, bf16x4);
        bf16x4 h1 = __builtin_convertvector(v1, bf16x4);
        *(bf16x8*)(abf16 + swz_ad(m, k, 1152)) =
            __builtin_shufflevector(h0, h1, 0,1,2,3,4,5,6,7);
    } else if (idx < 1253376) {          // wcat: 512 rows x 144 chunks
        int q = idx - 1179648;
        int n = q / 144;
        int k = (q - n * 144) * 8;
        const float* s;
        if (k < 128)      s = Wi2io  + n * 128 + k;
        else if (k < 640) s = Wio2io + n * 512 + (k - 128);
        else              s = Wcf2io + n * 512 + (k - 640);
        f32x4 v0 = *(const f32x4*)s;
        f32x4 v1 = *(const f32x4*)(s + 4);
        float w[8];
        #pragma unroll
        for (int t = 0; t < 4; ++t) { w[t] = 0.5f * v0[t]; w[t+4] = 0.5f * v1[t]; }
        #pragma unroll
        for (int t = 0; t < 8; ++t) {
            int kk = k + t;
            if (kk >= 128 && kk < 640 && (kk - 128) == n) w[t] += 0.5f;  // +0.5*I
        }
        unsigned short* dst = wcat + swz_ad(n, k, 1152);
        #pragma unroll
        for (int t = 0; t < 8; ++t) dst[t] = f2bf(w[t]);
    } else if (idx < 1261568) {          // w2s: 128 rows x 64 chunks
        int q = idx - 1253376;
        int n = q >> 6;
        int k = (q & 63) * 8;
        f32x4 v0 = *(const f32x4*)(Wio2o + n * 512 + k);
        f32x4 v1 = *(const f32x4*)(Wio2o + n * 512 + k + 4);
        bf16x4 h0 = __builtin_convertvector(v0, bf16x4);
        bf16x4 h1 = __builtin_convertvector(v1, bf16x4);
        *(bf16x8*)(w2s + swz_ad(n, k, 512)) =
            __builtin_shufflevector(h0, h1, 0,1,2,3,4,5,6,7);
    } else if (idx < 1262080) {
        int n = idx - 1261568;
        bsum[n] = 0.5f * (b1[n] + b2[n] + b3[n]);
    }
}

// ---------------------------------------------------------------------------
// Kernel 1: ionew = tanh(abf16 @ wcat^T + bsum), bf16 out (stored swizzled).
// M=8192 N=512 K=1152. BM=128 BN=128 BK=64, 512 thr (8 waves 4m x 2n, wave
// 32x64). Grid 256 = 1 block/CU, XCD-affine (8 panels x 4 colb per XCD).
// LDS 3 x (A bf16 16KB | B bf16 16KB) = 96KB. All staging via gl_lds from
// pre-swizzled global (linear offsets). 2 tiles ahead, WAITB(4) steady-state.
// ---------------------------------------------------------------------------
__global__ __launch_bounds__(512, 2) void k_gemm1(
    const unsigned short* __restrict__ abf16,
    const unsigned short* __restrict__ wcat,
    const float* __restrict__ bsum,
    unsigned short* __restrict__ ionew)
{
    __shared__ __align__(16) char lds[3][32768];   // A @0 (16KB), B @16384

    const int tid = threadIdx.x, b = blockIdx.x;
    const int xcd = b & 7, idx = b >> 3;           // idx 0..31
    const int m0 = ((xcd << 3) | (idx & 7)) << 7;  // panel*128
    const int n0 = (idx >> 3) << 7;                // colb*128

    const int lane = tid & 63, wid = tid >> 6;
    const int li = lane & 15, lh = lane >> 4;
    const int wm = (wid >> 1) << 5;       // 0/32/64/96
    const int wn = (wid & 1) << 6;        // 0/64

    // staging offsets (global pre-swizzled -> linear here). 16KB/tile each:
    // wave w covers rows [w*16, w*16+16) in 2 issues of 8 rows.
    int a_off[2], b_off[2];
    #pragma unroll
    for (int j = 0; j < 2; ++j) {
        int ra = (wid << 4) + (j << 3) + (lane >> 3);    // A row 0..127
        a_off[j] = (m0 + ra) * 1152 + ((lane & 7) << 3);
        int rb = (wid << 4) + (j << 3) + (lane >> 3);    // B row 0..127
        b_off[j] = (n0 + rb) * 1152 + ((lane & 7) << 3);
    }
    const int adst = wid << 11;          // + j<<10 (2KB per wave per region)

    f32x4 zz = {0.f, 0.f, 0.f, 0.f};
    f32x4 acc[2][4];
    #pragma unroll
    for (int i = 0; i < 2; ++i)
        #pragma unroll
        for (int j = 0; j < 4; ++j) acc[i][j] = zz;

#define STAGE1(KT, BUF) do {                                                   \
        int K_ = (KT);                                                         \
        char* A_ = (BUF); char* B_ = (BUF) + 16384;                            \
        const unsigned short* ap = abf16 + (K_ << 6);                          \
        gload16(ap + a_off[0], A_ + adst);                                     \
        gload16(ap + a_off[1], A_ + adst + 1024);                              \
        const unsigned short* wp = wcat + (K_ << 6);                           \
        gload16(wp + b_off[0], B_ + adst);                                     \
        gload16(wp + b_off[1], B_ + adst + 1024);                              \
    } while (0)

#define COMPUTE1(BUF) do {                                                     \
        const char* A_ = (BUF); const char* B_ = (BUF) + 16384;                \
        _Pragma("unroll")                                                      \
        for (int ks = 0; ks < 2; ++ks) {                                       \
            int c = ks * 4 + lh;                                               \
            bf16x8 af[2];                                                      \
            _Pragma("unroll")                                                  \
            for (int mi = 0; mi < 2; ++mi) {                                   \
                int r = wm + mi * 16 + li;                                     \
                af[mi] = *(const bf16x8*)(A_ + r * 128 + ((c ^ (r & 7)) << 4));\
            }                                                                  \
            _Pragma("unroll")                                                  \
            for (int nj = 0; nj < 4; ++nj) {                                   \
                int rb = wn + nj * 16 + li;                                    \
                bf16x8 bv = *(const bf16x8*)(B_ + rb * 128 +                   \
                                             ((c ^ (rb & 7)) << 4));           \
                acc[0][nj] = __builtin_amdgcn_mfma_f32_16x16x32_bf16(          \
                    af[0], bv, acc[0][nj], 0, 0, 0);                           \
                acc[1][nj] = __builtin_amdgcn_mfma_f32_16x16x32_bf16(          \
                    af[1], bv, acc[1][nj], 0, 0, 0);                           \
            }                                                                  \
        }                                                                      \
    } while (0)

    STAGE1(0, lds[0]);
    STAGE1(1, lds[1]);
    char* p0 = lds[0]; char* p1 = lds[1]; char* p2 = lds[2];
    #pragma unroll 1
    for (int t = 0; t < 18; ++t) {
        if (t < 17) { WAITB(4); } else { WAITB(0); }
        if (t + 2 < 18) STAGE1(t + 2, p2);   // 2 tiles ahead
        COMPUTE1(p0);
        char* tmp = p0; p0 = p1; p1 = p2; p2 = tmp;
    }
#undef STAGE1
#undef COMPUTE1

    // epilogue: bias+tanh, store bf16 chunk-swizzled (gemm2-ready layout)
    #pragma unroll
    for (int nj = 0; nj < 4; ++nj) {
        int gn = n0 + wn + nj * 16 + li;
        float bb = bsum[gn];
        #pragma unroll
        for (int mi = 0; mi < 2; ++mi) {
            #pragma unroll
            for (int r = 0; r < 4; ++r) {
                int gm = m0 + wm + mi * 16 + (lh << 2) + r;
                float v = tanh_fast(acc[mi][nj][r] + bb);
                ionew[swz_ad(gm, gn, 512)] = f2bf(v);
            }
        }
    }
}

// ---------------------------------------------------------------------------
// Kernel 2: y = tanh(ionew @ w2s^T + bio2o). M=8192 N=128 K=512.
// BM=32 BN=128(full) BK=64, 256 thr (4 waves, wave 32x32). Grid 256.
// 3-buffer counted pipeline (5 gl_lds/stage -> WAITB(5)). [r8, unchanged]
// ---------------------------------------------------------------------------
__global__ __launch_bounds__(256, 2) void k_gemm2(
    const unsigned short* __restrict__ ionew,
    const unsigned short* __restrict__ w2s,
    const float* __restrict__ b4,
    float* __restrict__ out)
{
    __shared__ __align__(16) char lds[3][20480];   // A @0 (4KB), B @4096 (16KB)

    const int tid = threadIdx.x, b = blockIdx.x;
    const int xcd = b & 7, idx = b >> 3;           // idx 0..31
    const int m0 = ((xcd << 5) | idx) << 5;        // matches gemm1 writer XCD

    const int lane = tid & 63, wid = tid >> 6;
    const int li = lane & 15, lh = lane >> 4;
    const int wn = wid << 5;                       // 32 out-cols per wave

    const int a2_off = (m0 + (wid << 3) + (lane >> 3)) * 512 + ((lane & 7) << 3);
    int b2_off[4];
    #pragma unroll
    for (int j = 0; j < 4; ++j)
        b2_off[j] = ((wid << 5) + 8 * j + (lane >> 3)) * 512 + ((lane & 7) << 3);

    f32x4 zz = {0.f, 0.f, 0.f, 0.f};
    f32x4 acc[2][2];
    acc[0][0] = zz; acc[0][1] = zz; acc[1][0] = zz; acc[1][1] = zz;

#define STAGE2(KT, BUF) do {                                                   \
        int K_ = (KT);                                                         \
        char* A_ = (BUF); char* B_ = (BUF) + 4096;                             \
        gload16(ionew + a2_off + (K_ << 6), A_ + (wid << 10));                 \
        _Pragma("unroll")                                                      \
        for (int j = 0; j < 4; ++j)                                            \
            gload16(w2s + b2_off[j] + (K_ << 6), B_ + (wid << 12) + j * 1024); \
    } while (0)

#define COMPUTE2(BUF) do {                                                     \
        const char* A_ = (BUF); const char* B_ = (BUF) + 4096;                 \
        _Pragma("unroll")                                                      \
        for (int ks = 0; ks < 2; ++ks) {                                       \
            int c = ks * 4 + lh;                                               \
            bf16x8 av[2];                                                      \
            _Pragma("unroll")                                                  \
            for (int mi = 0; mi < 2; ++mi) {                                   \
                int r = mi * 16 + li;                                          \
                av[mi] = *(const bf16x8*)(A_ + r * 128 + ((c ^ (r & 7)) << 4));\
            }                                                                  \
            _Pragma("unroll")                                                  \
            for (int nj = 0; nj < 2; ++nj) {                                   \
                int rb = wn + nj * 16 + li;                                    \
                bf16x8 bv = *(const bf16x8*)(B_ + rb * 128 +                   \
                                             ((c ^ (rb & 7)) << 4));           \
                acc[0][nj] = __builtin_amdgcn_mfma_f32_16x16x32_bf16(          \
                    av[0], bv, acc[0][nj], 0, 0, 0);                           \
                acc[1][nj] = __builtin_amdgcn_mfma_f32_16x16x32_bf16(          \
                    av[1], bv, acc[1][nj], 0, 0, 0);                           \
            }                                                                  \
        }                                                                      \
    } while (0)

    STAGE2(0, lds[0]);
    STAGE2(1, lds[1]);
    char* p0 = lds[0]; char* p1 = lds[1]; char* p2 = lds[2];
    #pragma unroll 1
    for (int t = 0; t < 7; ++t) {
        WAITB(5);
        if (t + 2 < 8) STAGE2(t + 2, p2);
        COMPUTE2(p0);
        char* tmp = p0; p0 = p1; p1 = p2; p2 = tmp;
    }
    WAITB(0);
    COMPUTE2(p0);                          // tile 7
#undef STAGE2
#undef COMPUTE2

    #pragma unroll
    for (int nj = 0; nj < 2; ++nj) {
        int n = wn + nj * 16 + li;
        float bb = b4[n];
        #pragma unroll
        for (int mi = 0; mi < 2; ++mi) {
            #pragma unroll
            for (int r = 0; r < 4; ++r) {
                int gm = m0 + mi * 16 + (lh << 2) + r;
                out[(size_t)gm * 128 + n] = tanh_fast(acc[mi][nj][r] + bb);
            }
        }
    }
}

// ---------------------------------------------------------------------------
extern "C" void kernel_launch(void* const* d_in, const int* in_sizes, int n_in,
                              void* d_out, int out_size, void* d_ws, size_t ws_size,
                              hipStream_t stream)
{
    const float* x      = (const float*)d_in[0];
    const float* io     = (const float*)d_in[1];
    const float* cf     = (const float*)d_in[2];
    // d_in[3] cs_state: dead (does not feed y)
    const float* Wi2io  = (const float*)d_in[4];
    const float* bi2io  = (const float*)d_in[5];
    const float* Wio2o  = (const float*)d_in[6];
    const float* bio2o  = (const float*)d_in[7];
    const float* Wio2io = (const float*)d_in[8];
    const float* bio2io = (const float*)d_in[9];
    const float* Wcf2io = (const float*)d_in[12];
    const float* bcf2io = (const float*)d_in[13];
    float* out = (float*)d_out;

    // ws: abf16 18,874,368 | wcat 1,179,648 | w2s 131,072 | bsum 2,048
    //   | ionew 8,388,608   (total ~28.6 MB)
    char* ws = (char*)d_ws;
    unsigned short* abf16 = (unsigned short*)ws;
    unsigned short* wcat  = (unsigned short*)(ws + 18874368);
    unsigned short* w2s   = (unsigned short*)(ws + 20054016);
    float*          bsum  = (float*)(ws + 20185088);
    unsigned short* ionew = (unsigned short*)(ws + 20187136);

    hipLaunchKernelGGL(k_prep, dim3(4930), dim3(256), 0, stream,
                       x, io, cf, Wi2io, Wio2io, Wcf2io, Wio2o,
                       bi2io, bio2io, bcf2io, abf16, wcat, w2s, bsum);
    hipLaunchKernelGGL(k_gemm1, dim3(256), dim3(512), 0, stream,
                       abf16, wcat, bsum, ionew);
    hipLaunchKernelGGL(k_gemm2, dim3(256), dim3(256), 0, stream,
                       ionew, w2s, bio2o, out);
}